// Round 5
// baseline (568.000 us; speedup 1.0000x reference)
//
#include <hip/hip_runtime.h>

#define N_NODES 100000
#define N_EDGES 1600000
#define D_FEAT 128
#define SCAN_BS 1024
#define SCAN_NB ((N_NODES + SCAN_BS - 1) / SCAN_BS)   /* 98 */

typedef unsigned int u32;
typedef unsigned short u16;
typedef __attribute__((ext_vector_type(8))) short bf16x8;
typedef __attribute__((ext_vector_type(4))) float f32x4;

__device__ inline float bfbits2f(u32 hi) { union { u32 u; float f; } v; v.u = hi; return v.f; }
__device__ inline float bflo(u32 pair) { return bfbits2f(pair << 16); }
__device__ inline float bfhi(u32 pair) { return bfbits2f(pair & 0xFFFF0000u); }
__device__ inline float bf1(u16 b) { return bfbits2f(((u32)b) << 16); }
__device__ inline u16 f2bf(float f) {
  union { float f; u32 u; } v; v.f = f;
  u32 r = v.u + 0x7FFFu + ((v.u >> 16) & 1u);
  return (u16)(r >> 16);
}
__device__ inline short f2bfs(float f) { return (short)f2bf(f); }

// ---- dtype probe. flags[0]=1 if x is bf16 (else f32). flags[1]=1 if edges int64 ----
__global__ __launch_bounds__(256) void k_detect(const u32* __restrict__ xw,
                                                const int* __restrict__ ei,
                                                int* __restrict__ flags) {
  __shared__ int cnt_bf, nz;
  if (threadIdx.x == 0) { cnt_bf = 0; nz = 0; }
  __syncthreads();
  int local = 0, acc = 0;
#pragma unroll
  for (int k = 0; k < 4; k++) {
    u32 w = xw[threadIdx.x * 4 + k];
    u32 e = (w >> 7) & 0xFFu;                 // exponent of LOW u16 viewed as bf16
    if (e >= 100u && e <= 140u) local++;      // N(0,1) bf16: ~always; f32 mantissa noise: ~16%
    acc |= ei[2 * (threadIdx.x * 4 + k) + 1]; // int64 edge data: high words are 0
  }
  atomicAdd(&cnt_bf, local);
  if (acc != 0) atomicOr(&nz, 1);
  __syncthreads();
  if (threadIdx.x == 0) { flags[0] = (cnt_bf > 900) ? 1 : 0; flags[1] = (nz == 0) ? 1 : 0; }
}

__device__ inline int edge_row(const int* ei, int is64, int e) {
  unsigned r = (unsigned)ei[is64 ? (long)2 * e : (long)e];
  return (r < N_NODES) ? (int)r : 0;
}
__device__ inline int edge_col(const int* ei, int is64, int e) {
  unsigned c = (unsigned)ei[is64 ? ((long)2 * N_EDGES + 2 * e) : ((long)N_EDGES + e)];
  return (c < N_NODES) ? (int)c : 0;
}

// ---------------- degree histogram ----------------
__global__ __launch_bounds__(256) void k_hist(const int* __restrict__ ei,
                                              const int* __restrict__ flags,
                                              int* __restrict__ deg) {
  int e = blockIdx.x * 256 + threadIdx.x;
  if (e >= N_EDGES) return;
  atomicAdd(&deg[edge_row(ei, flags[1], e)], 1);
}

// ---------------- scan (3 kernels) ----------------
__global__ __launch_bounds__(SCAN_BS) void k_scan1(const int* __restrict__ deg,
                                                   int* __restrict__ incl,
                                                   int* __restrict__ bsum) {
  __shared__ int sm[SCAN_BS];
  int i = blockIdx.x * SCAN_BS + threadIdx.x;
  int v = (i < N_NODES) ? deg[i] : 0;
  sm[threadIdx.x] = v;
  __syncthreads();
  for (int off = 1; off < SCAN_BS; off <<= 1) {
    int t = (threadIdx.x >= off) ? sm[threadIdx.x - off] : 0;
    __syncthreads();
    sm[threadIdx.x] += t;
    __syncthreads();
  }
  if (i < N_NODES) incl[i] = sm[threadIdx.x];
  if (threadIdx.x == SCAN_BS - 1) bsum[blockIdx.x] = sm[threadIdx.x];
}

__global__ __launch_bounds__(128) void k_scan2(int* __restrict__ bsum) {
  __shared__ int sm[128];
  int v = (threadIdx.x < SCAN_NB) ? bsum[threadIdx.x] : 0;
  sm[threadIdx.x] = v;
  __syncthreads();
  for (int off = 1; off < 128; off <<= 1) {
    int t = (threadIdx.x >= off) ? sm[threadIdx.x - off] : 0;
    __syncthreads();
    sm[threadIdx.x] += t;
    __syncthreads();
  }
  if (threadIdx.x < SCAN_NB) bsum[threadIdx.x] = sm[threadIdx.x] - v;  // exclusive
}

__global__ __launch_bounds__(SCAN_BS) void k_scan3(const int* __restrict__ deg,
                                                   const int* __restrict__ bsum,
                                                   int* __restrict__ row_start,
                                                   float* __restrict__ dis) {
  int i = blockIdx.x * SCAN_BS + threadIdx.x;
  if (i >= N_NODES) return;
  int d = deg[i];
  row_start[i] = row_start[i] - d + bsum[blockIdx.x];
  dis[i] = (d > 0) ? rsqrtf((float)d) : 0.0f;
}

// ---------------- CSR scatter ----------------
__global__ __launch_bounds__(256) void k_scatter(const int* __restrict__ ei,
                                                 const int* __restrict__ flags,
                                                 const int* __restrict__ row_start,
                                                 int* __restrict__ cursor,
                                                 int* __restrict__ csr_col) {
  int e = blockIdx.x * 256 + threadIdx.x;
  if (e >= N_EDGES) return;
  int is64 = flags[1];
  int r = edge_row(ei, is64, e);
  int p = row_start[r] + atomicAdd(&cursor[r], 1);
  csr_col[p] = edge_col(ei, is64, e);
}

// ================= f32 world =================
__global__ __launch_bounds__(256) void k_agg_f32(const int* __restrict__ flags,
                                                 const int* __restrict__ row_start,
                                                 const int* __restrict__ deg,
                                                 const int* __restrict__ csr_col,
                                                 const float* __restrict__ dis,
                                                 const float* __restrict__ x,
                                                 float* __restrict__ agg /* = d_out */) {
  if (flags[0] != 0) return;
  int wave = threadIdx.x >> 6, lane = threadIdx.x & 63;
  int r = blockIdx.x * 4 + wave;
  if (r >= N_NODES) return;
  int start = row_start[r];
  int cnt = deg[r];
  float dr = dis[r];
  float a0 = 0.f, a1 = 0.f;
  for (int i = 0; i < cnt; i++) {
    int c = csr_col[start + i];
    float nrm = dr * dis[c];
    float2 v = *(const float2*)(x + (long)c * D_FEAT + lane * 2);
    a0 += nrm * v.x;
    a1 += nrm * v.y;
  }
  float2 o; o.x = a0; o.y = a1;
  *(float2*)(agg + (long)r * D_FEAT + lane * 2) = o;
}

__global__ __launch_bounds__(256) void k_gemm_f32(const int* __restrict__ flags,
                                                  const float* __restrict__ x,
                                                  const float* __restrict__ Wself,
                                                  const float* __restrict__ Wnb,
                                                  const float* __restrict__ bias,
                                                  float* __restrict__ out /* agg on entry */) {
  if (flags[0] != 0) return;
  __shared__ __align__(16) u16 Wp[2 * 16 * 128 * 8];  // 64 KB, bf16-converted weights
  int tid = threadIdx.x;
  for (int base = tid; base < 128 * 128; base += 256) {
    int k = base >> 7, n = base & 127;
    int chunk = k >> 3, j = k & 7;
    Wp[((0 * 16 + chunk) * 128 + n) * 8 + j] = f2bf(Wself[k * 128 + n]);
    Wp[((1 * 16 + chunk) * 128 + n) * 8 + j] = f2bf(Wnb[k * 128 + n]);
  }
  __syncthreads();

  int wave = tid >> 6, lane = tid & 63;
  int q = lane >> 4, l16 = lane & 15;
  int m0 = blockIdx.x * 64 + wave * 16;
  int node_a = m0 + l16;
  long aoff = (long)(node_a < N_NODES ? node_a : 0) * D_FEAT;

  bf16x8 ax[4], ag[4];
#pragma unroll
  for (int kk = 0; kk < 4; kk++) {
#pragma unroll
    for (int j = 0; j < 8; j++) {
      ax[kk][j] = f2bfs(x[aoff + kk * 32 + q * 8 + j]);
      ag[kk][j] = f2bfs(out[aoff + kk * 32 + q * 8 + j]);
    }
  }

  f32x4 res[8];
#pragma unroll
  for (int nt = 0; nt < 8; nt++) {
    f32x4 acc = {0.f, 0.f, 0.f, 0.f};
#pragma unroll
    for (int kk = 0; kk < 4; kk++) {
      bf16x8 bs = *(const bf16x8*)(&Wp[((0 * 16 + kk * 4 + q) * 128 + nt * 16 + l16) * 8]);
      acc = __builtin_amdgcn_mfma_f32_16x16x32_bf16(ax[kk], bs, acc, 0, 0, 0);
    }
#pragma unroll
    for (int kk = 0; kk < 4; kk++) {
      bf16x8 bn = *(const bf16x8*)(&Wp[((1 * 16 + kk * 4 + q) * 128 + nt * 16 + l16) * 8]);
      acc = __builtin_amdgcn_mfma_f32_16x16x32_bf16(ag[kk], bn, acc, 0, 0, 0);
    }
    res[nt] = acc;
  }

#pragma unroll
  for (int nt = 0; nt < 8; nt++) {
    int ncol = nt * 16 + l16;
    float bv = bias[ncol];
#pragma unroll
    for (int reg = 0; reg < 4; reg++) {
      int node = m0 + q * 4 + reg;
      if (node < N_NODES) out[(long)node * D_FEAT + ncol] = res[nt][reg] + bv;
    }
  }
}

// ================= bf16 world =================
__global__ __launch_bounds__(256) void k_agg_bf16(const int* __restrict__ flags,
                                                  const int* __restrict__ row_start,
                                                  const int* __restrict__ deg,
                                                  const int* __restrict__ csr_col,
                                                  const float* __restrict__ dis,
                                                  const u16* __restrict__ x,
                                                  u16* __restrict__ agg /* = d_out */) {
  if (flags[0] != 1) return;
  int wave = threadIdx.x >> 6, lane = threadIdx.x & 63;
  int r = blockIdx.x * 4 + wave;
  if (r >= N_NODES) return;
  int start = row_start[r];
  int cnt = deg[r];
  float dr = dis[r];
  float a0 = 0.f, a1 = 0.f;
  for (int i = 0; i < cnt; i++) {
    int c = csr_col[start + i];
    float nrm = dr * dis[c];
    u32 hv = *(const u32*)(x + (long)c * D_FEAT + lane * 2);
    a0 += nrm * bflo(hv);
    a1 += nrm * bfhi(hv);
  }
  u32 pack = (u32)f2bf(a0) | ((u32)f2bf(a1) << 16);
  *(u32*)(agg + (long)r * D_FEAT + lane * 2) = pack;
}

__global__ __launch_bounds__(256) void k_gemm_bf16(const int* __restrict__ flags,
                                                   const u16* __restrict__ x,
                                                   const u16* __restrict__ Wself,
                                                   const u16* __restrict__ Wnb,
                                                   const u16* __restrict__ bias,
                                                   u16* __restrict__ out /* agg on entry */) {
  if (flags[0] != 1) return;
  __shared__ __align__(16) u16 Wp[2 * 16 * 128 * 8];  // 64 KB
  int tid = threadIdx.x;
  for (int base = tid; base < 128 * 128; base += 256) {
    int k = base >> 7, n = base & 127;
    int chunk = k >> 3, j = k & 7;
    Wp[((0 * 16 + chunk) * 128 + n) * 8 + j] = Wself[k * 128 + n];
    Wp[((1 * 16 + chunk) * 128 + n) * 8 + j] = Wnb[k * 128 + n];
  }
  __syncthreads();

  int wave = tid >> 6, lane = tid & 63;
  int q = lane >> 4, l16 = lane & 15;
  int m0 = blockIdx.x * 64 + wave * 16;
  int node_a = m0 + l16;
  long aoff = (long)(node_a < N_NODES ? node_a : 0) * D_FEAT;

  bf16x8 ax[4], ag[4];
#pragma unroll
  for (int kk = 0; kk < 4; kk++) {
    ax[kk] = *(const bf16x8*)(x + aoff + kk * 32 + q * 8);
    ag[kk] = *(const bf16x8*)(out + aoff + kk * 32 + q * 8);
  }

  f32x4 res[8];
#pragma unroll
  for (int nt = 0; nt < 8; nt++) {
    f32x4 acc = {0.f, 0.f, 0.f, 0.f};
#pragma unroll
    for (int kk = 0; kk < 4; kk++) {
      bf16x8 bs = *(const bf16x8*)(&Wp[((0 * 16 + kk * 4 + q) * 128 + nt * 16 + l16) * 8]);
      acc = __builtin_amdgcn_mfma_f32_16x16x32_bf16(ax[kk], bs, acc, 0, 0, 0);
    }
#pragma unroll
    for (int kk = 0; kk < 4; kk++) {
      bf16x8 bn = *(const bf16x8*)(&Wp[((1 * 16 + kk * 4 + q) * 128 + nt * 16 + l16) * 8]);
      acc = __builtin_amdgcn_mfma_f32_16x16x32_bf16(ag[kk], bn, acc, 0, 0, 0);
    }
    res[nt] = acc;
  }

#pragma unroll
  for (int nt = 0; nt < 8; nt++) {
    int ncol = nt * 16 + l16;
    float bv = bf1(bias[ncol]);
#pragma unroll
    for (int reg = 0; reg < 4; reg++) {
      int node = m0 + q * 4 + reg;
      if (node < N_NODES) out[(long)node * D_FEAT + ncol] = f2bf(res[nt][reg] + bv);
    }
  }
}

extern "C" void kernel_launch(void* const* d_in, const int* in_sizes, int n_in,
                              void* d_out, int out_size, void* d_ws, size_t ws_size,
                              hipStream_t stream) {
  const void* xv = d_in[0];
  const int* ei = (const int*)d_in[1];
  const void* Wsv = d_in[2];
  const void* Wnv = d_in[3];
  const void* bv = d_in[4];

  auto alignup = [](size_t v) { return (v + 511) & ~(size_t)511; };
  char* p = (char*)d_ws;
  int* deg = (int*)p;            p += alignup((size_t)N_NODES * 4);
  int* cursor = (int*)p;         p += alignup((size_t)N_NODES * 4);
  int* row_start = (int*)p;      p += alignup((size_t)N_NODES * 4);
  int* bsum = (int*)p;           p += alignup((size_t)SCAN_NB * 4);
  float* dis = (float*)p;        p += alignup((size_t)N_NODES * 4);
  int* flags = (int*)p;          p += alignup((size_t)512);
  int* csr_col = (int*)p;        p += alignup((size_t)N_EDGES * 4);
  // ~7.6 MB total

  hipMemsetAsync(deg, 0, (size_t)N_NODES * 4, stream);
  hipMemsetAsync(cursor, 0, (size_t)N_NODES * 4, stream);

  k_detect<<<1, 256, 0, stream>>>((const u32*)xv, ei, flags);
  k_hist<<<(N_EDGES + 255) / 256, 256, 0, stream>>>(ei, flags, deg);
  k_scan1<<<SCAN_NB, SCAN_BS, 0, stream>>>(deg, row_start, bsum);
  k_scan2<<<1, 128, 0, stream>>>(bsum);
  k_scan3<<<SCAN_NB, SCAN_BS, 0, stream>>>(deg, bsum, row_start, dis);
  k_scatter<<<(N_EDGES + 255) / 256, 256, 0, stream>>>(ei, flags, row_start, cursor, csr_col);

  // f32 world
  k_agg_f32<<<(N_NODES + 3) / 4, 256, 0, stream>>>(flags, row_start, deg, csr_col, dis,
                                                   (const float*)xv, (float*)d_out);
  k_gemm_f32<<<(N_NODES + 63) / 64, 256, 0, stream>>>(flags, (const float*)xv,
                                                      (const float*)Wsv, (const float*)Wnv,
                                                      (const float*)bv, (float*)d_out);
  // bf16 world
  k_agg_bf16<<<(N_NODES + 3) / 4, 256, 0, stream>>>(flags, row_start, deg, csr_col, dis,
                                                    (const u16*)xv, (u16*)d_out);
  k_gemm_bf16<<<(N_NODES + 63) / 64, 256, 0, stream>>>(flags, (const u16*)xv,
                                                       (const u16*)Wsv, (const u16*)Wnv,
                                                       (const u16*)bv, (u16*)d_out);
}

// Round 6
// 413.230 us; speedup vs baseline: 1.3745x; 1.3745x over previous
//
#include <hip/hip_runtime.h>

#define N_NODES 100000
#define N_EDGES 1600000
#define D_FEAT 128
#define SCAN_BS 1024
#define SCAN_NB ((N_NODES + SCAN_BS - 1) / SCAN_BS)   /* 98 */

typedef unsigned int u32;
typedef unsigned short u16;
typedef __attribute__((ext_vector_type(8))) short bf16x8;
typedef __attribute__((ext_vector_type(4))) float f32x4;

__device__ inline float bfbits2f(u32 hi) { union { u32 u; float f; } v; v.u = hi; return v.f; }
__device__ inline float bflo(u32 pair) { return bfbits2f(pair << 16); }
__device__ inline float bfhi(u32 pair) { return bfbits2f(pair & 0xFFFF0000u); }
__device__ inline u16 f2bf(float f) {
  union { float f; u32 u; } v; v.f = f;
  u32 r = v.u + 0x7FFFu + ((v.u >> 16) & 1u);
  return (u16)(r >> 16);
}
__device__ inline short f2bfs(float f) { return (short)f2bf(f); }
__device__ inline int clampN(int v) { return ((unsigned)v < N_NODES) ? v : 0; }

// ---- x f32 -> bf16 (packed pairs), one float4 -> uint2 per thread ----
__global__ __launch_bounds__(256) void k_conv(const float4* __restrict__ x4,
                                              uint2* __restrict__ xb2) {
  int i = blockIdx.x * 256 + threadIdx.x;
  if (i >= N_NODES * D_FEAT / 4) return;
  float4 v = x4[i];
  uint2 o;
  o.x = (u32)f2bf(v.x) | ((u32)f2bf(v.y) << 16);
  o.y = (u32)f2bf(v.z) | ((u32)f2bf(v.w) << 16);
  xb2[i] = o;
}

// ---------------- degree histogram (edges int32) ----------------
__global__ __launch_bounds__(256) void k_hist(const int* __restrict__ ei, int* __restrict__ deg) {
  int e = blockIdx.x * 256 + threadIdx.x;
  if (e < N_EDGES) atomicAdd(&deg[clampN(ei[e])], 1);
}

// ---------------- scan (3 kernels) ----------------
__global__ __launch_bounds__(SCAN_BS) void k_scan1(const int* __restrict__ deg,
                                                   int* __restrict__ incl,
                                                   int* __restrict__ bsum) {
  __shared__ int sm[SCAN_BS];
  int i = blockIdx.x * SCAN_BS + threadIdx.x;
  int v = (i < N_NODES) ? deg[i] : 0;
  sm[threadIdx.x] = v;
  __syncthreads();
  for (int off = 1; off < SCAN_BS; off <<= 1) {
    int t = (threadIdx.x >= off) ? sm[threadIdx.x - off] : 0;
    __syncthreads();
    sm[threadIdx.x] += t;
    __syncthreads();
  }
  if (i < N_NODES) incl[i] = sm[threadIdx.x];
  if (threadIdx.x == SCAN_BS - 1) bsum[blockIdx.x] = sm[threadIdx.x];
}

__global__ __launch_bounds__(128) void k_scan2(int* __restrict__ bsum) {
  __shared__ int sm[128];
  int v = (threadIdx.x < SCAN_NB) ? bsum[threadIdx.x] : 0;
  sm[threadIdx.x] = v;
  __syncthreads();
  for (int off = 1; off < 128; off <<= 1) {
    int t = (threadIdx.x >= off) ? sm[threadIdx.x - off] : 0;
    __syncthreads();
    sm[threadIdx.x] += t;
    __syncthreads();
  }
  if (threadIdx.x < SCAN_NB) bsum[threadIdx.x] = sm[threadIdx.x] - v;  // exclusive
}

__global__ __launch_bounds__(SCAN_BS) void k_scan3(const int* __restrict__ deg,
                                                   const int* __restrict__ bsum,
                                                   int* __restrict__ row_start,
                                                   float* __restrict__ dis) {
  int i = blockIdx.x * SCAN_BS + threadIdx.x;
  if (i >= N_NODES) return;
  int d = deg[i];
  row_start[i] = row_start[i] - d + bsum[blockIdx.x];
  dis[i] = (d > 0) ? rsqrtf((float)d) : 0.0f;
}

// -------- CSR scatter with fused per-edge norm: cn[p] = (col, norm) --------
__global__ __launch_bounds__(256) void k_scatter(const int* __restrict__ ei,
                                                 const int* __restrict__ row_start,
                                                 int* __restrict__ cursor,
                                                 const float* __restrict__ dis,
                                                 int2* __restrict__ cn) {
  int e = blockIdx.x * 256 + threadIdx.x;
  if (e >= N_EDGES) return;
  int r = clampN(ei[e]);
  int c = clampN(ei[N_EDGES + e]);
  int p = row_start[r] + atomicAdd(&cursor[r], 1);
  int2 rec;
  rec.x = c;
  rec.y = __float_as_int(dis[r] * dis[c]);
  cn[p] = rec;
}

// -------- aggregation: agg[r] = sum_e norm * xb[col]  (f32 out into d_out) --------
// One wave per row; lane covers feature pair (2*lane, 2*lane+1). Edge loop
// unrolled x4 for gather-latency overlap.
__global__ __launch_bounds__(256) void k_agg(const int* __restrict__ row_start,
                                             const int* __restrict__ deg,
                                             const int2* __restrict__ cn,
                                             const u32* __restrict__ xb /* u32 pairs, stride 64 */,
                                             float* __restrict__ out) {
  int wave = threadIdx.x >> 6, lane = threadIdx.x & 63;
  int r = blockIdx.x * 4 + wave;
  if (r >= N_NODES) return;
  int start = row_start[r];
  int cnt = deg[r];
  float a0 = 0.f, a1 = 0.f;
  int i = 0;
  for (; i + 4 <= cnt; i += 4) {
    int2 e0 = cn[start + i];
    int2 e1 = cn[start + i + 1];
    int2 e2 = cn[start + i + 2];
    int2 e3 = cn[start + i + 3];
    u32 g0 = xb[(long)e0.x * 64 + lane];
    u32 g1 = xb[(long)e1.x * 64 + lane];
    u32 g2 = xb[(long)e2.x * 64 + lane];
    u32 g3 = xb[(long)e3.x * 64 + lane];
    float n0 = __int_as_float(e0.y), n1 = __int_as_float(e1.y);
    float n2 = __int_as_float(e2.y), n3 = __int_as_float(e3.y);
    a0 += n0 * bflo(g0); a1 += n0 * bfhi(g0);
    a0 += n1 * bflo(g1); a1 += n1 * bfhi(g1);
    a0 += n2 * bflo(g2); a1 += n2 * bfhi(g2);
    a0 += n3 * bflo(g3); a1 += n3 * bfhi(g3);
  }
  for (; i < cnt; i++) {
    int2 e0 = cn[start + i];
    u32 g0 = xb[(long)e0.x * 64 + lane];
    float n0 = __int_as_float(e0.y);
    a0 += n0 * bflo(g0); a1 += n0 * bfhi(g0);
  }
  float2 o; o.x = a0; o.y = a1;
  *(float2*)(out + (long)r * D_FEAT + lane * 2) = o;
}

// -------- fused GEMM: out = x@Wself + agg@Wnb + bias (in-place on d_out) --------
// x read as bf16 vectors from xb; agg read as f32 vectors from out (each wave
// touches only its own 16 rows for both reads and writes -> in-place safe).
__global__ __launch_bounds__(256) void k_gemm(const u16* __restrict__ xb,
                                              const float* __restrict__ Wself,
                                              const float* __restrict__ Wnb,
                                              const float* __restrict__ bias,
                                              float* __restrict__ out /* agg on entry */) {
  __shared__ __align__(16) u16 Wp[2 * 16 * 128 * 8];  // 64 KB, bf16 weights, B-frag order
  int tid = threadIdx.x;
  for (int base = tid; base < 128 * 128; base += 256) {
    int k = base >> 7, n = base & 127;
    int chunk = k >> 3, j = k & 7;
    Wp[((0 * 16 + chunk) * 128 + n) * 8 + j] = f2bf(Wself[k * 128 + n]);
    Wp[((1 * 16 + chunk) * 128 + n) * 8 + j] = f2bf(Wnb[k * 128 + n]);
  }
  __syncthreads();

  int wave = tid >> 6, lane = tid & 63;
  int q = lane >> 4, l16 = lane & 15;
  int m0 = blockIdx.x * 64 + wave * 16;
  int node_a = m0 + l16;
  long aoff = (long)(node_a < N_NODES ? node_a : 0) * D_FEAT;

  bf16x8 ax[4], ag[4];
#pragma unroll
  for (int kk = 0; kk < 4; kk++) {
    ax[kk] = *(const bf16x8*)(xb + aoff + kk * 32 + q * 8);
    f32x4 u = *(const f32x4*)(out + aoff + kk * 32 + q * 8);
    f32x4 v = *(const f32x4*)(out + aoff + kk * 32 + q * 8 + 4);
    bf16x8 t;
    t[0] = f2bfs(u[0]); t[1] = f2bfs(u[1]); t[2] = f2bfs(u[2]); t[3] = f2bfs(u[3]);
    t[4] = f2bfs(v[0]); t[5] = f2bfs(v[1]); t[6] = f2bfs(v[2]); t[7] = f2bfs(v[3]);
    ag[kk] = t;
  }

  f32x4 res[8];
#pragma unroll
  for (int nt = 0; nt < 8; nt++) {
    f32x4 acc = {0.f, 0.f, 0.f, 0.f};
#pragma unroll
    for (int kk = 0; kk < 4; kk++) {
      bf16x8 bs = *(const bf16x8*)(&Wp[((0 * 16 + kk * 4 + q) * 128 + nt * 16 + l16) * 8]);
      acc = __builtin_amdgcn_mfma_f32_16x16x32_bf16(ax[kk], bs, acc, 0, 0, 0);
    }
#pragma unroll
    for (int kk = 0; kk < 4; kk++) {
      bf16x8 bn = *(const bf16x8*)(&Wp[((1 * 16 + kk * 4 + q) * 128 + nt * 16 + l16) * 8]);
      acc = __builtin_amdgcn_mfma_f32_16x16x32_bf16(ag[kk], bn, acc, 0, 0, 0);
    }
    res[nt] = acc;
  }

  // C layout: col = lane&15 (n), row = q*4 + reg (m)
#pragma unroll
  for (int nt = 0; nt < 8; nt++) {
    int ncol = nt * 16 + l16;
    float bv = bias[ncol];
#pragma unroll
    for (int reg = 0; reg < 4; reg++) {
      int node = m0 + q * 4 + reg;
      if (node < N_NODES) out[(long)node * D_FEAT + ncol] = res[nt][reg] + bv;
    }
  }
}

extern "C" void kernel_launch(void* const* d_in, const int* in_sizes, int n_in,
                              void* d_out, int out_size, void* d_ws, size_t ws_size,
                              hipStream_t stream) {
  const float* x = (const float*)d_in[0];
  const int* ei = (const int*)d_in[1];         // int32 (confirmed R5: f32 world ran+passed)
  const float* Wself = (const float*)d_in[2];
  const float* Wnb = (const float*)d_in[3];
  const float* bias = (const float*)d_in[4];
  float* out = (float*)d_out;

  auto alignup = [](size_t v) { return (v + 511) & ~(size_t)511; };
  char* p = (char*)d_ws;
  int* deg = (int*)p;            p += alignup((size_t)N_NODES * 4);
  int* cursor = (int*)p;         p += alignup((size_t)N_NODES * 4);
  int* row_start = (int*)p;      p += alignup((size_t)N_NODES * 4);
  int* bsum = (int*)p;           p += alignup((size_t)SCAN_NB * 4);
  float* dis = (float*)p;        p += alignup((size_t)N_NODES * 4);
  int2* cn = (int2*)p;           p += alignup((size_t)N_EDGES * 8);       // 12.8 MB
  u16* xb = (u16*)p;             p += alignup((size_t)N_NODES * D_FEAT * 2); // 25.6 MB
  // total ~40.4 MB (R1 demonstrated >= 66 MB mapped)

  hipMemsetAsync(deg, 0, (size_t)N_NODES * 4, stream);
  hipMemsetAsync(cursor, 0, (size_t)N_NODES * 4, stream);

  k_conv<<<(N_NODES * D_FEAT / 4 + 255) / 256, 256, 0, stream>>>((const float4*)x, (uint2*)xb);
  k_hist<<<(N_EDGES + 255) / 256, 256, 0, stream>>>(ei, deg);
  k_scan1<<<SCAN_NB, SCAN_BS, 0, stream>>>(deg, row_start, bsum);
  k_scan2<<<1, 128, 0, stream>>>(bsum);
  k_scan3<<<SCAN_NB, SCAN_BS, 0, stream>>>(deg, bsum, row_start, dis);
  k_scatter<<<(N_EDGES + 255) / 256, 256, 0, stream>>>(ei, row_start, cursor, dis, cn);
  k_agg<<<(N_NODES + 3) / 4, 256, 0, stream>>>(row_start, deg, cn, (const u32*)xb, out);
  k_gemm<<<(N_NODES + 63) / 64, 256, 0, stream>>>(xb, Wself, Wnb, bias, out);
}

// Round 7
// 366.864 us; speedup vs baseline: 1.5483x; 1.1264x over previous
//
#include <hip/hip_runtime.h>

#define N_NODES 100000
#define N_EDGES 1600000
#define D_FEAT 128
#define SCAN_BS 1024
#define SCAN_NB ((N_NODES + SCAN_BS - 1) / SCAN_BS)   /* 98 */

typedef unsigned int u32;
typedef unsigned short u16;
typedef __attribute__((ext_vector_type(8))) short bf16x8;
typedef __attribute__((ext_vector_type(4))) float f32x4;

__device__ inline float bfbits2f(u32 hi) { union { u32 u; float f; } v; v.u = hi; return v.f; }
__device__ inline float bflo(u32 pair) { return bfbits2f(pair << 16); }
__device__ inline float bfhi(u32 pair) { return bfbits2f(pair & 0xFFFF0000u); }
__device__ inline u16 f2bf(float f) {
  union { float f; u32 u; } v; v.f = f;
  u32 r = v.u + 0x7FFFu + ((v.u >> 16) & 1u);
  return (u16)(r >> 16);
}
__device__ inline int clampN(int v) { return ((unsigned)v < N_NODES) ? v : 0; }

// ---- x f32 -> bf16 (packed pairs) ----
__global__ __launch_bounds__(256) void k_conv(const float4* __restrict__ x4,
                                              uint2* __restrict__ xb2) {
  int i = blockIdx.x * 256 + threadIdx.x;
  if (i >= N_NODES * D_FEAT / 4) return;
  float4 v = x4[i];
  uint2 o;
  o.x = (u32)f2bf(v.x) | ((u32)f2bf(v.y) << 16);
  o.y = (u32)f2bf(v.z) | ((u32)f2bf(v.w) << 16);
  xb2[i] = o;
}

// ---- weights f32 -> bf16 in B-fragment-linear order ----
// Wbf entry index f = ((t*4 + kk)*8 + nt)*64 + lane ; 8 bf16 elems j=0..7:
//   W_t[k][n], k = (kk*4 + q)*8 + j, n = nt*16 + l16   (q=lane>>4, l16=lane&15)
__global__ __launch_bounds__(256) void k_wprep(const float* __restrict__ Wself,
                                               const float* __restrict__ Wnb,
                                               u16* __restrict__ Wbf) {
  int f = blockIdx.x * 256 + threadIdx.x;   // 4096 entries
  if (f >= 4096) return;
  int lane = f & 63, nt = (f >> 6) & 7, kk = (f >> 9) & 3, t = f >> 11;
  int q = lane >> 4, l16 = lane & 15;
  const float* W = t ? Wnb : Wself;
  int n = nt * 16 + l16;
  int k0 = (kk * 4 + q) * 8;
  u16 tmp[8];
#pragma unroll
  for (int j = 0; j < 8; j++) tmp[j] = f2bf(W[(k0 + j) * 128 + n]);
  uint4 o;
  o.x = (u32)tmp[0] | ((u32)tmp[1] << 16);
  o.y = (u32)tmp[2] | ((u32)tmp[3] << 16);
  o.z = (u32)tmp[4] | ((u32)tmp[5] << 16);
  o.w = (u32)tmp[6] | ((u32)tmp[7] << 16);
  *(uint4*)(Wbf + (long)f * 8) = o;
}

// ---------------- degree histogram (edges int32) ----------------
__global__ __launch_bounds__(256) void k_hist(const int* __restrict__ ei, int* __restrict__ deg) {
  int e = blockIdx.x * 256 + threadIdx.x;
  if (e < N_EDGES) atomicAdd(&deg[clampN(ei[e])], 1);
}

// ---------------- scan (3 kernels) ----------------
__global__ __launch_bounds__(SCAN_BS) void k_scan1(const int* __restrict__ deg,
                                                   int* __restrict__ incl,
                                                   int* __restrict__ bsum) {
  __shared__ int sm[SCAN_BS];
  int i = blockIdx.x * SCAN_BS + threadIdx.x;
  int v = (i < N_NODES) ? deg[i] : 0;
  sm[threadIdx.x] = v;
  __syncthreads();
  for (int off = 1; off < SCAN_BS; off <<= 1) {
    int t = (threadIdx.x >= off) ? sm[threadIdx.x - off] : 0;
    __syncthreads();
    sm[threadIdx.x] += t;
    __syncthreads();
  }
  if (i < N_NODES) incl[i] = sm[threadIdx.x];
  if (threadIdx.x == SCAN_BS - 1) bsum[blockIdx.x] = sm[threadIdx.x];
}

__global__ __launch_bounds__(128) void k_scan2(int* __restrict__ bsum) {
  __shared__ int sm[128];
  int v = (threadIdx.x < SCAN_NB) ? bsum[threadIdx.x] : 0;
  sm[threadIdx.x] = v;
  __syncthreads();
  for (int off = 1; off < 128; off <<= 1) {
    int t = (threadIdx.x >= off) ? sm[threadIdx.x - off] : 0;
    __syncthreads();
    sm[threadIdx.x] += t;
    __syncthreads();
  }
  if (threadIdx.x < SCAN_NB) bsum[threadIdx.x] = sm[threadIdx.x] - v;  // exclusive
}

__global__ __launch_bounds__(SCAN_BS) void k_scan3(const int* __restrict__ deg,
                                                   const int* __restrict__ bsum,
                                                   int* __restrict__ row_start,
                                                   float* __restrict__ dis) {
  int i = blockIdx.x * SCAN_BS + threadIdx.x;
  if (i >= N_NODES) return;
  int d = deg[i];
  row_start[i] = row_start[i] - d + bsum[blockIdx.x];
  dis[i] = (d > 0) ? rsqrtf((float)d) : 0.0f;
}

// -------- CSR scatter with fused per-edge norm: cn[p] = (col, norm) --------
__global__ __launch_bounds__(256) void k_scatter(const int* __restrict__ ei,
                                                 const int* __restrict__ row_start,
                                                 int* __restrict__ cursor,
                                                 const float* __restrict__ dis,
                                                 int2* __restrict__ cn) {
  int e = blockIdx.x * 256 + threadIdx.x;
  if (e >= N_EDGES) return;
  int r = clampN(ei[e]);
  int c = clampN(ei[N_EDGES + e]);
  int p = row_start[r] + atomicAdd(&cursor[r], 1);
  int2 rec;
  rec.x = c;
  rec.y = __float_as_int(dis[r] * dis[c]);
  cn[p] = rec;
}

// -------- aggregation: aggb[r] = bf16( sum_e norm * xb[col] ) --------
__global__ __launch_bounds__(256) void k_agg(const int* __restrict__ row_start,
                                             const int* __restrict__ deg,
                                             const int2* __restrict__ cn,
                                             const u32* __restrict__ xb /* pairs, stride 64 */,
                                             u32* __restrict__ aggb) {
  int wave = threadIdx.x >> 6, lane = threadIdx.x & 63;
  int r = blockIdx.x * 4 + wave;
  if (r >= N_NODES) return;
  int start = row_start[r];
  int cnt = deg[r];
  float a0 = 0.f, a1 = 0.f;
  int i = 0;
  for (; i + 4 <= cnt; i += 4) {
    int2 e0 = cn[start + i];
    int2 e1 = cn[start + i + 1];
    int2 e2 = cn[start + i + 2];
    int2 e3 = cn[start + i + 3];
    u32 g0 = xb[(long)e0.x * 64 + lane];
    u32 g1 = xb[(long)e1.x * 64 + lane];
    u32 g2 = xb[(long)e2.x * 64 + lane];
    u32 g3 = xb[(long)e3.x * 64 + lane];
    float n0 = __int_as_float(e0.y), n1 = __int_as_float(e1.y);
    float n2 = __int_as_float(e2.y), n3 = __int_as_float(e3.y);
    a0 += n0 * bflo(g0); a1 += n0 * bfhi(g0);
    a0 += n1 * bflo(g1); a1 += n1 * bfhi(g1);
    a0 += n2 * bflo(g2); a1 += n2 * bfhi(g2);
    a0 += n3 * bflo(g3); a1 += n3 * bfhi(g3);
  }
  for (; i < cnt; i++) {
    int2 e0 = cn[start + i];
    u32 g0 = xb[(long)e0.x * 64 + lane];
    float n0 = __int_as_float(e0.y);
    a0 += n0 * bflo(g0); a1 += n0 * bfhi(g0);
  }
  aggb[(long)r * 64 + lane] = (u32)f2bf(a0) | ((u32)f2bf(a1) << 16);
}

// -------- GEMM: out = x@Wself + agg@Wnb + bias. No LDS; B-frags from global ----
// Block = 4 waves x 32 nodes = 128 nodes. Wave holds A-frags for 2 m-tiles in
// regs; nt-outer loop loads each B-frag once (coalesced 16B/lane from Wbf).
__global__ __launch_bounds__(256) void k_gemm(const u16* __restrict__ xb,
                                              const u16* __restrict__ aggb,
                                              const u16* __restrict__ Wbf,
                                              const float* __restrict__ bias,
                                              float* __restrict__ out) {
  int tid = threadIdx.x;
  int wave = tid >> 6, lane = tid & 63;
  int q = lane >> 4, l16 = lane & 15;
  int w0 = blockIdx.x * 128 + wave * 32;

  bf16x8 ax[2][4], ag[2][4];
#pragma unroll
  for (int mt = 0; mt < 2; mt++) {
    int node = w0 + mt * 16 + l16;
    long aoff = (long)clampN(node) * D_FEAT + q * 8;
#pragma unroll
    for (int kk = 0; kk < 4; kk++) {
      ax[mt][kk] = *(const bf16x8*)(xb + aoff + kk * 32);
      ag[mt][kk] = *(const bf16x8*)(aggb + aoff + kk * 32);
    }
  }

#pragma unroll
  for (int nt = 0; nt < 8; nt++) {
    bf16x8 bs[4], bn[4];
#pragma unroll
    for (int kk = 0; kk < 4; kk++) {
      bs[kk] = *(const bf16x8*)(Wbf + (long)(((0 * 4 + kk) * 8 + nt) * 64 + lane) * 8);
      bn[kk] = *(const bf16x8*)(Wbf + (long)(((1 * 4 + kk) * 8 + nt) * 64 + lane) * 8);
    }
    int ncol = nt * 16 + l16;
    float bv = bias[ncol];
#pragma unroll
    for (int mt = 0; mt < 2; mt++) {
      f32x4 acc = {0.f, 0.f, 0.f, 0.f};
#pragma unroll
      for (int kk = 0; kk < 4; kk++)
        acc = __builtin_amdgcn_mfma_f32_16x16x32_bf16(ax[mt][kk], bs[kk], acc, 0, 0, 0);
#pragma unroll
      for (int kk = 0; kk < 4; kk++)
        acc = __builtin_amdgcn_mfma_f32_16x16x32_bf16(ag[mt][kk], bn[kk], acc, 0, 0, 0);
      // C layout: col = l16, row(m) = q*4 + reg
#pragma unroll
      for (int reg = 0; reg < 4; reg++) {
        int node = w0 + mt * 16 + q * 4 + reg;
        if (node < N_NODES) out[(long)node * D_FEAT + ncol] = acc[reg] + bv;
      }
    }
  }
}

extern "C" void kernel_launch(void* const* d_in, const int* in_sizes, int n_in,
                              void* d_out, int out_size, void* d_ws, size_t ws_size,
                              hipStream_t stream) {
  const float* x = (const float*)d_in[0];
  const int* ei = (const int*)d_in[1];         // int32 (confirmed R5)
  const float* Wself = (const float*)d_in[2];
  const float* Wnb = (const float*)d_in[3];
  const float* bias = (const float*)d_in[4];
  float* out = (float*)d_out;

  auto alignup = [](size_t v) { return (v + 511) & ~(size_t)511; };
  char* p = (char*)d_ws;
  int* deg = (int*)p;            p += alignup((size_t)N_NODES * 4);
  int* cursor = (int*)p;         p += alignup((size_t)N_NODES * 4);
  int* row_start = (int*)p;      p += alignup((size_t)N_NODES * 4);
  int* bsum = (int*)p;           p += alignup((size_t)SCAN_NB * 4);
  float* dis = (float*)p;        p += alignup((size_t)N_NODES * 4);
  u16* Wbf = (u16*)p;            p += alignup((size_t)4096 * 8 * 2);          // 64 KB
  int2* cn = (int2*)p;           p += alignup((size_t)N_EDGES * 8);           // 12.8 MB
  u16* xb = (u16*)p;             p += alignup((size_t)N_NODES * D_FEAT * 2);  // 25.6 MB
  u16* aggb = (u16*)p;           p += alignup((size_t)N_NODES * D_FEAT * 2);  // 25.6 MB
  // total ~66 MB (R1 demonstrated this much is mapped+writable)

  hipMemsetAsync(deg, 0, (size_t)N_NODES * 4, stream);
  hipMemsetAsync(cursor, 0, (size_t)N_NODES * 4, stream);

  k_conv<<<(N_NODES * D_FEAT / 4 + 255) / 256, 256, 0, stream>>>((const float4*)x, (uint2*)xb);
  k_wprep<<<16, 256, 0, stream>>>(Wself, Wnb, Wbf);
  k_hist<<<(N_EDGES + 255) / 256, 256, 0, stream>>>(ei, deg);
  k_scan1<<<SCAN_NB, SCAN_BS, 0, stream>>>(deg, row_start, bsum);
  k_scan2<<<1, 128, 0, stream>>>(bsum);
  k_scan3<<<SCAN_NB, SCAN_BS, 0, stream>>>(deg, bsum, row_start, dis);
  k_scatter<<<(N_EDGES + 255) / 256, 256, 0, stream>>>(ei, row_start, cursor, dis, cn);
  k_agg<<<(N_NODES + 3) / 4, 256, 0, stream>>>(row_start, deg, cn, (const u32*)xb, (u32*)aggb);
  k_gemm<<<(N_NODES + 127) / 128, 256, 0, stream>>>(xb, aggb, Wbf, bias, out);
}

// Round 8
// 327.542 us; speedup vs baseline: 1.7341x; 1.1201x over previous
//
#include <hip/hip_runtime.h>

#define N_NODES 100000
#define N_EDGES 1600000
#define D_FEAT 128
#define SCAN_BS 1024
#define SCAN_NB ((N_NODES + SCAN_BS - 1) / SCAN_BS)   /* 98 */
#define BUCKETS 256
#define RPB 391            /* rows per bucket; 256*391 = 100096 >= 100000 */
#define BIN_CHUNK 8192
#define BIN_WGS ((N_EDGES + BIN_CHUNK - 1) / BIN_CHUNK)  /* 196 */
#define CSR_CAP 12288      /* LDS window records; bucket mean 6250, sd ~80 */

typedef unsigned int u32;
typedef unsigned short u16;
typedef __attribute__((ext_vector_type(8))) short bf16x8;
typedef __attribute__((ext_vector_type(4))) float f32x4;

__device__ inline float bfbits2f(u32 hi) { union { u32 u; float f; } v; v.u = hi; return v.f; }
__device__ inline float bflo(u32 pair) { return bfbits2f(pair << 16); }
__device__ inline float bfhi(u32 pair) { return bfbits2f(pair & 0xFFFF0000u); }
__device__ inline u16 f2bf(float f) {
  union { float f; u32 u; } v; v.f = f;
  u32 r = v.u + 0x7FFFu + ((v.u >> 16) & 1u);
  return (u16)(r >> 16);
}
__device__ inline int clampN(int v) { return ((unsigned)v < N_NODES) ? v : 0; }

// ---- x f32 -> bf16 (packed pairs) ----
__global__ __launch_bounds__(256) void k_conv(const float4* __restrict__ x4,
                                              uint2* __restrict__ xb2) {
  int i = blockIdx.x * 256 + threadIdx.x;
  if (i >= N_NODES * D_FEAT / 4) return;
  float4 v = x4[i];
  uint2 o;
  o.x = (u32)f2bf(v.x) | ((u32)f2bf(v.y) << 16);
  o.y = (u32)f2bf(v.z) | ((u32)f2bf(v.w) << 16);
  xb2[i] = o;
}

// ---- weights f32 -> bf16 in B-fragment-linear order ----
__global__ __launch_bounds__(256) void k_wprep(const float* __restrict__ Wself,
                                               const float* __restrict__ Wnb,
                                               u16* __restrict__ Wbf) {
  int f = blockIdx.x * 256 + threadIdx.x;   // 4096 entries
  if (f >= 4096) return;
  int lane = f & 63, nt = (f >> 6) & 7, kk = (f >> 9) & 3, t = f >> 11;
  int q = lane >> 4, l16 = lane & 15;
  const float* W = t ? Wnb : Wself;
  int n = nt * 16 + l16;
  int k0 = (kk * 4 + q) * 8;
  u16 tmp[8];
#pragma unroll
  for (int j = 0; j < 8; j++) tmp[j] = f2bf(W[(k0 + j) * 128 + n]);
  uint4 o;
  o.x = (u32)tmp[0] | ((u32)tmp[1] << 16);
  o.y = (u32)tmp[2] | ((u32)tmp[3] << 16);
  o.z = (u32)tmp[4] | ((u32)tmp[5] << 16);
  o.w = (u32)tmp[6] | ((u32)tmp[7] << 16);
  *(uint4*)(Wbf + (long)f * 8) = o;
}

// ---------------- degree histogram (edges int32) ----------------
__global__ __launch_bounds__(256) void k_hist(const int* __restrict__ ei, int* __restrict__ deg) {
  int e = blockIdx.x * 256 + threadIdx.x;
  if (e < N_EDGES) atomicAdd(&deg[clampN(ei[e])], 1);
}

// ---------------- scan (3 kernels) ----------------
__global__ __launch_bounds__(SCAN_BS) void k_scan1(const int* __restrict__ deg,
                                                   int* __restrict__ incl,
                                                   int* __restrict__ bsum) {
  __shared__ int sm[SCAN_BS];
  int i = blockIdx.x * SCAN_BS + threadIdx.x;
  int v = (i < N_NODES) ? deg[i] : 0;
  sm[threadIdx.x] = v;
  __syncthreads();
  for (int off = 1; off < SCAN_BS; off <<= 1) {
    int t = (threadIdx.x >= off) ? sm[threadIdx.x - off] : 0;
    __syncthreads();
    sm[threadIdx.x] += t;
    __syncthreads();
  }
  if (i < N_NODES) incl[i] = sm[threadIdx.x];
  if (threadIdx.x == SCAN_BS - 1) bsum[blockIdx.x] = sm[threadIdx.x];
}

__global__ __launch_bounds__(128) void k_scan2(int* __restrict__ bsum) {
  __shared__ int sm[128];
  int v = (threadIdx.x < SCAN_NB) ? bsum[threadIdx.x] : 0;
  sm[threadIdx.x] = v;
  __syncthreads();
  for (int off = 1; off < 128; off <<= 1) {
    int t = (threadIdx.x >= off) ? sm[threadIdx.x - off] : 0;
    __syncthreads();
    sm[threadIdx.x] += t;
    __syncthreads();
  }
  if (threadIdx.x < SCAN_NB) bsum[threadIdx.x] = sm[threadIdx.x] - v;  // exclusive
}

__global__ __launch_bounds__(SCAN_BS) void k_scan3(const int* __restrict__ deg,
                                                   const int* __restrict__ bsum,
                                                   int* __restrict__ row_start,
                                                   float* __restrict__ dis) {
  int i = blockIdx.x * SCAN_BS + threadIdx.x;
  if (i >= N_NODES) return;
  int d = deg[i];
  row_start[i] = row_start[i] - d + bsum[blockIdx.x];
  dis[i] = (d > 0) ? rsqrtf((float)d) : 0.0f;
}

// ---- init per-bucket global cursors from row_start ----
__global__ __launch_bounds__(256) void k_ginit(const int* __restrict__ row_start,
                                               int* __restrict__ gcur) {
  int b = threadIdx.x;
  if (b < BUCKETS) gcur[b] = row_start[b * RPB];   // 255*391 = 99705 < 100000
}

// ---- level-1: bin edges by bucket=row/RPB, WG-local LDS counting sort,
//      bucket-contiguous coalesced flush (single-producer lines) ----
__global__ __launch_bounds__(256) void k_bin(const int* __restrict__ ei,
                                             int* __restrict__ gcur,
                                             u32* __restrict__ binrec) {
  __shared__ int hist[BUCKETS], pref[BUCKETS], lcur[BUCKETS], gbase[BUCKETS];
  __shared__ u32 stag[BIN_CHUNK];
  __shared__ unsigned char sbkt[BIN_CHUNK];
  int tid = threadIdx.x;
  long e0 = (long)blockIdx.x * BIN_CHUNK;
  hist[tid] = 0;
  lcur[tid] = 0;
  __syncthreads();
  int rows[BIN_CHUNK / 256];
#pragma unroll
  for (int j = 0; j < BIN_CHUNK / 256; j++) {
    long e = e0 + j * 256 + tid;
    int r = (e < N_EDGES) ? clampN(ei[e]) : -1;
    rows[j] = r;
    if (r >= 0) atomicAdd(&hist[r / RPB], 1);
  }
  __syncthreads();
  int v = hist[tid];
  pref[tid] = v;
  __syncthreads();
  for (int off = 1; off < BUCKETS; off <<= 1) {
    int t = (tid >= off) ? pref[tid - off] : 0;
    __syncthreads();
    pref[tid] += t;
    __syncthreads();
  }
  int excl = pref[tid] - v;
  gbase[tid] = atomicAdd(&gcur[tid], v);   // reserve global range for this WG's bucket segment
  __syncthreads();
  pref[tid] = excl;                        // exclusive prefix = staging segment start
  __syncthreads();
#pragma unroll
  for (int j = 0; j < BIN_CHUNK / 256; j++) {
    int r = rows[j];
    if (r < 0) continue;
    long e = e0 + j * 256 + tid;
    int c = clampN(ei[N_EDGES + e]);
    int b = r / RPB;
    int rl = r - b * RPB;
    int pos = pref[b] + atomicAdd(&lcur[b], 1);
    stag[pos] = ((u32)rl << 17) | (u32)c;
    sbkt[pos] = (unsigned char)b;
  }
  __syncthreads();
  int total = pref[BUCKETS - 1] + hist[BUCKETS - 1];
  for (int i = tid; i < total; i += 256) {
    int b = sbkt[i];
    binrec[(long)gbase[b] + (i - pref[b])] = stag[i];
  }
}

// ---- level-2: per-bucket CSR placement in LDS window, coalesced out ----
__global__ __launch_bounds__(256) void k_csr(const int* __restrict__ row_start,
                                             const float* __restrict__ dis,
                                             const u32* __restrict__ binrec,
                                             int2* __restrict__ cn) {
  __shared__ int cur[RPB + 1];
  __shared__ int2 win[CSR_CAP];   // 96 KB
  int tid = threadIdx.x;
  int b = blockIdx.x;
  int r0 = b * RPB;
  int r1 = min(r0 + RPB, N_NODES);
  int base = row_start[r0];
  int end = (r1 >= N_NODES) ? N_EDGES : row_start[r1];
  int cnt = end - base;
  int nrows = r1 - r0;
  for (int i = tid; i < nrows; i += 256) cur[i] = row_start[r0 + i] - base;
  __syncthreads();
  if (cnt <= CSR_CAP) {
    for (int i = tid; i < cnt; i += 256) {
      u32 rec = binrec[base + i];
      int rl = rec >> 17;
      int c = rec & 0x1FFFF;
      float nrm = dis[r0 + rl] * dis[c];
      int p = atomicAdd(&cur[rl], 1);
      int2 o; o.x = c; o.y = __float_as_int(nrm);
      win[p] = o;
    }
    __syncthreads();
    for (int i = tid; i < cnt; i += 256) cn[base + i] = win[i];
  } else {  // statistically impossible fallback (binomial mean 6250, cap 12288)
    for (int i = tid; i < cnt; i += 256) {
      u32 rec = binrec[base + i];
      int rl = rec >> 17;
      int c = rec & 0x1FFFF;
      float nrm = dis[r0 + rl] * dis[c];
      int p = base + atomicAdd(&cur[rl], 1);
      int2 o; o.x = c; o.y = __float_as_int(nrm);
      cn[p] = o;
    }
  }
}

// -------- aggregation: aggb[r] = bf16( sum_e norm * xb[col] ) --------
__global__ __launch_bounds__(256) void k_agg(const int* __restrict__ row_start,
                                             const int* __restrict__ deg,
                                             const int2* __restrict__ cn,
                                             const u32* __restrict__ xb /* pairs, stride 64 */,
                                             u32* __restrict__ aggb) {
  int wave = threadIdx.x >> 6, lane = threadIdx.x & 63;
  int r = blockIdx.x * 4 + wave;
  if (r >= N_NODES) return;
  int start = row_start[r];
  int cnt = deg[r];
  float a0 = 0.f, a1 = 0.f;
  int i = 0;
  for (; i + 4 <= cnt; i += 4) {
    int2 e0 = cn[start + i];
    int2 e1 = cn[start + i + 1];
    int2 e2 = cn[start + i + 2];
    int2 e3 = cn[start + i + 3];
    u32 g0 = xb[(long)e0.x * 64 + lane];
    u32 g1 = xb[(long)e1.x * 64 + lane];
    u32 g2 = xb[(long)e2.x * 64 + lane];
    u32 g3 = xb[(long)e3.x * 64 + lane];
    float n0 = __int_as_float(e0.y), n1 = __int_as_float(e1.y);
    float n2 = __int_as_float(e2.y), n3 = __int_as_float(e3.y);
    a0 += n0 * bflo(g0); a1 += n0 * bfhi(g0);
    a0 += n1 * bflo(g1); a1 += n1 * bfhi(g1);
    a0 += n2 * bflo(g2); a1 += n2 * bfhi(g2);
    a0 += n3 * bflo(g3); a1 += n3 * bfhi(g3);
  }
  for (; i < cnt; i++) {
    int2 e0 = cn[start + i];
    u32 g0 = xb[(long)e0.x * 64 + lane];
    float n0 = __int_as_float(e0.y);
    a0 += n0 * bflo(g0); a1 += n0 * bfhi(g0);
  }
  aggb[(long)r * 64 + lane] = (u32)f2bf(a0) | ((u32)f2bf(a1) << 16);
}

// -------- GEMM: out = x@Wself + agg@Wnb + bias. No LDS; B-frags from global ----
__global__ __launch_bounds__(256) void k_gemm(const u16* __restrict__ xb,
                                              const u16* __restrict__ aggb,
                                              const u16* __restrict__ Wbf,
                                              const float* __restrict__ bias,
                                              float* __restrict__ out) {
  int tid = threadIdx.x;
  int wave = tid >> 6, lane = tid & 63;
  int q = lane >> 4, l16 = lane & 15;
  int w0 = blockIdx.x * 128 + wave * 32;

  bf16x8 ax[2][4], ag[2][4];
#pragma unroll
  for (int mt = 0; mt < 2; mt++) {
    int node = w0 + mt * 16 + l16;
    long aoff = (long)clampN(node) * D_FEAT + q * 8;
#pragma unroll
    for (int kk = 0; kk < 4; kk++) {
      ax[mt][kk] = *(const bf16x8*)(xb + aoff + kk * 32);
      ag[mt][kk] = *(const bf16x8*)(aggb + aoff + kk * 32);
    }
  }

#pragma unroll
  for (int nt = 0; nt < 8; nt++) {
    bf16x8 bs[4], bn[4];
#pragma unroll
    for (int kk = 0; kk < 4; kk++) {
      bs[kk] = *(const bf16x8*)(Wbf + (long)(((0 * 4 + kk) * 8 + nt) * 64 + lane) * 8);
      bn[kk] = *(const bf16x8*)(Wbf + (long)(((1 * 4 + kk) * 8 + nt) * 64 + lane) * 8);
    }
    int ncol = nt * 16 + l16;
    float bv = bias[ncol];
#pragma unroll
    for (int mt = 0; mt < 2; mt++) {
      f32x4 acc = {0.f, 0.f, 0.f, 0.f};
#pragma unroll
      for (int kk = 0; kk < 4; kk++)
        acc = __builtin_amdgcn_mfma_f32_16x16x32_bf16(ax[mt][kk], bs[kk], acc, 0, 0, 0);
#pragma unroll
      for (int kk = 0; kk < 4; kk++)
        acc = __builtin_amdgcn_mfma_f32_16x16x32_bf16(ag[mt][kk], bn[kk], acc, 0, 0, 0);
#pragma unroll
      for (int reg = 0; reg < 4; reg++) {
        int node = w0 + mt * 16 + q * 4 + reg;
        if (node < N_NODES) out[(long)node * D_FEAT + ncol] = acc[reg] + bv;
      }
    }
  }
}

extern "C" void kernel_launch(void* const* d_in, const int* in_sizes, int n_in,
                              void* d_out, int out_size, void* d_ws, size_t ws_size,
                              hipStream_t stream) {
  const float* x = (const float*)d_in[0];
  const int* ei = (const int*)d_in[1];         // int32 (confirmed R5)
  const float* Wself = (const float*)d_in[2];
  const float* Wnb = (const float*)d_in[3];
  const float* bias = (const float*)d_in[4];
  float* out = (float*)d_out;

  auto alignup = [](size_t v) { return (v + 511) & ~(size_t)511; };
  char* p = (char*)d_ws;
  int* deg = (int*)p;            p += alignup((size_t)N_NODES * 4);
  int* row_start = (int*)p;      p += alignup((size_t)N_NODES * 4);
  int* bsum = (int*)p;           p += alignup((size_t)SCAN_NB * 4);
  float* dis = (float*)p;        p += alignup((size_t)N_NODES * 4);
  int* gcur = (int*)p;           p += alignup((size_t)BUCKETS * 4);
  u16* Wbf = (u16*)p;            p += alignup((size_t)4096 * 8 * 2);          // 64 KB
  int2* cn = (int2*)p;           p += alignup((size_t)N_EDGES * 8);           // 12.8 MB
  u16* xb = (u16*)p;             p += alignup((size_t)N_NODES * D_FEAT * 2);  // 25.6 MB
  u16* aggb = (u16*)p;           p += alignup((size_t)N_NODES * D_FEAT * 2);  // 25.6 MB
  // ~65.3 MB of d_ws (<= R7's proven 66 MB footprint)
  u32* binrec = (u32*)d_out;     // 6.4 MB staged in d_out; dead before k_gemm writes it

  hipMemsetAsync(deg, 0, (size_t)N_NODES * 4, stream);

  k_conv<<<(N_NODES * D_FEAT / 4 + 255) / 256, 256, 0, stream>>>((const float4*)x, (uint2*)xb);
  k_wprep<<<16, 256, 0, stream>>>(Wself, Wnb, Wbf);
  k_hist<<<(N_EDGES + 255) / 256, 256, 0, stream>>>(ei, deg);
  k_scan1<<<SCAN_NB, SCAN_BS, 0, stream>>>(deg, row_start, bsum);
  k_scan2<<<1, 128, 0, stream>>>(bsum);
  k_scan3<<<SCAN_NB, SCAN_BS, 0, stream>>>(deg, bsum, row_start, dis);
  k_ginit<<<1, 256, 0, stream>>>(row_start, gcur);
  k_bin<<<BIN_WGS, 256, 0, stream>>>(ei, gcur, binrec);
  k_csr<<<BUCKETS, 256, 0, stream>>>(row_start, dis, binrec, cn);
  k_agg<<<(N_NODES + 3) / 4, 256, 0, stream>>>(row_start, deg, cn, (const u32*)xb, (u32*)aggb);
  k_gemm<<<(N_NODES + 127) / 128, 256, 0, stream>>>(xb, aggb, Wbf, bias, out);
}